// Round 12
// baseline (216.748 us; speedup 1.0000x reference)
//
#include <hip/hip_runtime.h>
#include <hip/hip_bf16.h>

#define WDIM 192
#define PLANE (192 * 192)
#define VOL (192 * 192 * 192)
#define HC 24          // h-rows produced per block in wh_pass
#define TR (HC + 8)    // tile rows incl. halo = 32
#define NCH 8          // h-chunks per plane (192/HC) -> XCD class == chunk
#define RWU 100        // uints per padded LDS row: 200 f16 = [2 pad][96 data][2 pad] pairs
#define DC 24          // d-slices per block in d_pass

typedef __fp16 h2f __attribute__((ext_vector_type(2)));
typedef unsigned int u32x2 __attribute__((ext_vector_type(2)));

// ---- f16 helpers (wh_pass LDS staging + dot2 window sums) ----
static __device__ inline unsigned int pk_h16(float a, float b) {
    h2f v = __builtin_amdgcn_cvt_pkrtz(a, b);
    return __builtin_bit_cast(unsigned int, v);
}
// f32 += dot(f16pair, f16pair)
static __device__ inline float dot2u(unsigned int a, unsigned int b, float c) {
    return __builtin_amdgcn_fdot2(__builtin_bit_cast(h2f, a),
                                  __builtin_bit_cast(h2f, b), c, false);
}

// ---- bf16 record helpers (B format; unpack is pure bit-ops in d_pass) ----
static __device__ inline unsigned int pk_bf16(float a, float b) {
    union { __hip_bfloat162 v; unsigned int u; } cvt;
    cvt.v = __float22bfloat162_rn(make_float2(a, b));
    return cvt.u;
}
static __device__ inline float bf_lo(unsigned int u) {
    union { unsigned int u; float f; } c; c.u = u << 16; return c.f;
}
static __device__ inline float bf_hi(unsigned int u) {
    union { unsigned int u; float f; } c; c.u = u & 0xffff0000u; return c.f;
}

// --- Pass 1: fused W-box + H-box sums -> split-stream records --------------
// B2[idx] = {bf16(s0,s1), bf16(s2,s3)} (8B), B1[idx] = bf16(s4,_) (4B).
// CACHED stores (nt cost wh ~11us of drain backpressure, R9/R11).
// XCD-LOCALITY: block index = d*8 + c -> dispatch class (index%8) == c for
// every plane, so all records of h-rows [24c,24c+24) live on XCD c's L2.
// d_pass uses the matching mapping so its reads never cross XCDs.
// grid (1536, nb): x = d*8 + c, y = batch.
__global__ __launch_bounds__(192) void wh_pass(const float* __restrict__ I,
                                               const float* __restrict__ J,
                                               u32x2* __restrict__ B2,
                                               unsigned int* __restrict__ B1,
                                               float* __restrict__ out0) {
    __shared__ unsigned int sI[TR * RWU];   // 12800 B
    __shared__ unsigned int sJ[TR * RWU];   // 12800 B
    const int t = threadIdx.x;           // w
    const int d = blockIdx.x >> 3;
    const int c = blockIdx.x & 7;
    const int h0 = c * HC;

    // fold output zeroing into this dispatch (stream-ordered before d_pass)
    if (out0 && blockIdx.x == 0 && blockIdx.y == 0 && t == 0) *out0 = 0.0f;

    const size_t bofs = (size_t)blockIdx.y * VOL;
    const float* Ib = I + bofs;
    const float* Jb = J + bofs;
    u32x2* B2b = B2 + bofs;
    unsigned int* B1b = B1 + bofs;

    const size_t dbase = (size_t)d * PLANE;

    // zero the 4 pad pair-slots of each row in both arrays (TR*8 = 256)
    for (int n = t; n < TR * 8; n += 192) {
        const int row = n >> 3;
        const int p = n & 7;
        unsigned int* dst = (p < 4) ? sI : sJ;
        const int q = p & 3;
        const int col = (q < 2) ? q : (96 + q);   // {0,1,98,99}
        dst[row * RWU + col] = 0u;
    }

    // cooperative staging: rows 0..31, data pairs at uint index 2 + w/2
    #pragma unroll
    for (int i = 0; i < TR * 48 / 192; ++i) {    // 8 iters
        const int idx4 = i * 192 + t;        // 0..1535
        const int row  = idx4 / 48;          // 0..31
        const int col4 = (idx4 - row * 48) * 4;
        const int h = h0 - 4 + row;
        float4 vI = make_float4(0.f, 0.f, 0.f, 0.f);
        float4 vJ = vI;
        if (h >= 0 && h < WDIM) {
            vI = *(const float4*)(Ib + dbase + (size_t)h * WDIM + col4);
            vJ = *(const float4*)(Jb + dbase + (size_t)h * WDIM + col4);
        }
        uint2 uI, uJ;
        uI.x = pk_h16(vI.x, vI.y); uI.y = pk_h16(vI.z, vI.w);
        uJ.x = pk_h16(vJ.x, vJ.y); uJ.y = pk_h16(vJ.z, vJ.w);
        const int ui = row * RWU + 2 + (col4 >> 1);   // even -> 8B aligned
        *(uint2*)&sI[ui] = uI;
        *(uint2*)&sJ[ui] = uJ;
    }
    __syncthreads();

    // window for output w=t covers f16 elements E=t..t+8 -> pairs tb..tb+4
    const int tb = t >> 1;
    const int odd = t & 1;
    const unsigned int ONESF = 0x3C003C00u;                       // (1,1) f16
    const unsigned int ones0 = odd ? 0x3C000000u : ONESF;         // edge ones
    const unsigned int ones4 = odd ? ONESF : 0x00003C00u;
    const unsigned int keep0 = odd ? 0xFFFF0000u : 0xFFFFFFFFu;   // operand masks
    const unsigned int keep4 = odd ? 0xFFFFFFFFu : 0x0000FFFFu;

    float ring0[9], ring1[9], ring2[9], ring3[9], ring4[9];
    #pragma unroll
    for (int j = 0; j < 9; ++j) { ring0[j]=0.f; ring1[j]=0.f; ring2[j]=0.f; ring3[j]=0.f; ring4[j]=0.f; }
    float s0 = 0.f, s1 = 0.f, s2 = 0.f, s3 = 0.f, s4 = 0.f;

    unsigned int AI[5], AJ[5], BI[5], BJ[5];
    #pragma unroll
    for (int p = 0; p < 5; ++p) { AI[p] = sI[tb + p]; AJ[p] = sJ[tb + p]; }

    #pragma unroll
    for (int s = 0; s < TR; ++s) {
        if (s + 1 < TR) {
            const int base = (s + 1) * RWU + tb;
            if ((s & 1) == 0) {
                #pragma unroll
                for (int p = 0; p < 5; ++p) { BI[p] = sI[base + p]; BJ[p] = sJ[base + p]; }
            } else {
                #pragma unroll
                for (int p = 0; p < 5; ++p) { AI[p] = sI[base + p]; AJ[p] = sJ[base + p]; }
            }
        }
        const unsigned int c0 = ((s & 1) == 0) ? AI[0] : BI[0];
        const unsigned int c1 = ((s & 1) == 0) ? AI[1] : BI[1];
        const unsigned int c2 = ((s & 1) == 0) ? AI[2] : BI[2];
        const unsigned int c3 = ((s & 1) == 0) ? AI[3] : BI[3];
        const unsigned int c4 = ((s & 1) == 0) ? AI[4] : BI[4];
        const unsigned int e0 = ((s & 1) == 0) ? AJ[0] : BJ[0];
        const unsigned int e1 = ((s & 1) == 0) ? AJ[1] : BJ[1];
        const unsigned int e2 = ((s & 1) == 0) ? AJ[2] : BJ[2];
        const unsigned int e3 = ((s & 1) == 0) ? AJ[3] : BJ[3];
        const unsigned int e4 = ((s & 1) == 0) ? AJ[4] : BJ[4];

        const unsigned int mI0 = c0 & keep0, mI4 = c4 & keep4;
        const unsigned int mJ0 = e0 & keep0, mJ4 = e4 & keep4;

        float w0 = dot2u(c0, ones0, 0.f);
        w0 = dot2u(c1, ONESF, w0); w0 = dot2u(c2, ONESF, w0);
        w0 = dot2u(c3, ONESF, w0); w0 = dot2u(c4, ones4, w0);

        float w1 = dot2u(e0, ones0, 0.f);
        w1 = dot2u(e1, ONESF, w1); w1 = dot2u(e2, ONESF, w1);
        w1 = dot2u(e3, ONESF, w1); w1 = dot2u(e4, ones4, w1);

        float w2 = dot2u(mI0, c0, 0.f);
        w2 = dot2u(c1, c1, w2); w2 = dot2u(c2, c2, w2);
        w2 = dot2u(c3, c3, w2); w2 = dot2u(mI4, c4, w2);

        float w3 = dot2u(mJ0, e0, 0.f);
        w3 = dot2u(e1, e1, w3); w3 = dot2u(e2, e2, w3);
        w3 = dot2u(e3, e3, w3); w3 = dot2u(mJ4, e4, w3);

        float w4 = dot2u(mI0, e0, 0.f);
        w4 = dot2u(c1, e1, w4); w4 = dot2u(c2, e2, w4);
        w4 = dot2u(c3, e3, w4); w4 = dot2u(mI4, e4, w4);

        const int j = s % 9;
        s0 += w0 - ring0[j]; ring0[j] = w0;
        s1 += w1 - ring1[j]; ring1[j] = w1;
        s2 += w2 - ring2[j]; ring2[j] = w2;
        s3 += w3 - ring3[j]; ring3[j] = w3;
        s4 += w4 - ring4[j]; ring4[j] = w4;

        if (s >= 8) {
            const int h_out = h0 + s - 8;
            const size_t idx = dbase + (size_t)h_out * WDIM + t;
            u32x2 v2; v2.x = pk_bf16(s0, s1); v2.y = pk_bf16(s2, s3);
            B2b[idx] = v2;                      // cached dwordx2
            B1b[idx] = pk_bf16(s4, 0.f);        // cached dword
        }
    }
}

// --- Pass 2: D-axis sliding box sum + NCC + reduction ----------------------
// XCD-matched mapping: class g = bid%8 == h/24 == the XCD that wrote (and
// still holds) this row's records and center lines. Zero cross-XCD reads.
// R5-measured structure: DC=24, f32 rings, 4 groups of 8, register prefetch.
__global__ __launch_bounds__(192) void d_pass(const u32x2* __restrict__ B2,
                                              const unsigned int* __restrict__ B1,
                                              const float* __restrict__ I,
                                              const float* __restrict__ J,
                                              float* __restrict__ out) {
    const int t = threadIdx.x;
    const int g = blockIdx.x & 7;          // XCD class == writer chunk h/24
    const int q = blockIdx.x >> 3;         // 0..191
    const int h = g * HC + (q % HC);       // row within this class's 24 rows
    const int c = q / HC;                  // d-chunk 0..7
    const int d0 = c * DC;
    const int base_h = h * WDIM + t;

    const size_t bofs = (size_t)blockIdx.y * VOL;
    const float* Ib = I + bofs;
    const float* Jb = J + bofs;
    const u32x2* B2b = B2 + bofs;
    const unsigned int* B1b = B1 + bofs;

    float r0[9], r1[9], r2[9], r3[9], r4[9];
    #pragma unroll
    for (int j = 0; j < 9; ++j) { r0[j]=0.f; r1[j]=0.f; r2[j]=0.f; r3[j]=0.f; r4[j]=0.f; }
    float s0 = 0.f, s1 = 0.f, s2 = 0.f, s3 = 0.f, s4 = 0.f;

    const float inv_k = 1.0f / 729.0f;
    float local = 0.f;

    uint3 qA[8], qB[8];
    float2 cA[8], cB[8];
    // preload group 0 records (steps 0..7, d_in = d0-4 .. d0+3); no outputs yet
    #pragma unroll
    for (int i = 0; i < 8; ++i) {
        const int d_in = d0 - 4 + i;
        qA[i] = make_uint3(0u, 0u, 0u);
        if (d_in >= 0 && d_in < WDIM) {
            const size_t pos = (size_t)d_in * PLANE + base_h;
            const u32x2 v2 = B2b[pos];
            qA[i] = make_uint3(v2.x, v2.y, B1b[pos]);
        }
        cA[i] = make_float2(0.f, 0.f);
    }

    #pragma unroll
    for (int gg = 0; gg < 4; ++gg) {
        // prefetch group gg+1: records + centers
        if (gg + 1 < 4) {
            #pragma unroll
            for (int i = 0; i < 8; ++i) {
                const int s = (gg + 1) * 8 + i;
                const int d_in = d0 - 4 + s;
                uint3 v = make_uint3(0u, 0u, 0u);
                if (d_in >= 0 && d_in < WDIM) {
                    const size_t pos = (size_t)d_in * PLANE + base_h;
                    const u32x2 v2 = B2b[pos];
                    v = make_uint3(v2.x, v2.y, B1b[pos]);
                }
                const int d_out = d0 + s - 8;              // always in [0,192)
                const size_t cidx = (size_t)d_out * PLANE + base_h;
                const float ci = Ib[cidx];
                const float cj = Jb[cidx];
                if ((gg & 1) == 0) { qB[i] = v; cB[i] = make_float2(ci, cj); }
                else               { qA[i] = v; cA[i] = make_float2(ci, cj); }
            }
        }
        // process group gg
        #pragma unroll
        for (int i = 0; i < 8; ++i) {
            const int s = gg * 8 + i;
            const uint3 qv = ((gg & 1) == 0) ? qA[i] : qB[i];
            const float f0 = bf_lo(qv.x), f1 = bf_hi(qv.x);
            const float f2 = bf_lo(qv.y), f3 = bf_hi(qv.y);
            const float f4 = bf_lo(qv.z);
            const int j = s % 9;
            s0 += f0 - r0[j]; r0[j] = f0;
            s1 += f1 - r1[j]; r1[j] = f1;
            s2 += f2 - r2[j]; r2[j] = f2;
            s3 += f3 - r3[j]; r3[j] = f3;
            s4 += f4 - r4[j]; r4[j] = f4;

            if (s >= 8) {
                const float2 cc = ((gg & 1) == 0) ? cA[i] : cB[i];
                const float Iu = cc.x * inv_k;
                const float Ju = cc.y * inv_k;
                const float cross = s4 - s0 * Ju - s1 * Iu + Iu * Ju * 729.0f;
                const float Ivar  = s2 - 2.0f * s0 * Iu + Iu * Iu * 729.0f;
                const float Jvar  = s3 - 2.0f * s1 * Ju + Ju * Ju * 729.0f;
                local += (cross * cross) * __builtin_amdgcn_rcpf(Ivar * Jvar + 1e-5f);
            }
        }
    }

    __shared__ float sred[192];
    sred[t] = local;
    __syncthreads();
    if (t < 64) {
        float v = sred[t] + sred[t + 64] + sred[t + 128];
        #pragma unroll
        for (int off = 32; off; off >>= 1) v += __shfl_down(v, off);
        if (t == 0) {
            atomicAdd(out, v * (-1.0f / 14155776.0f));
        }
    }
}

extern "C" void kernel_launch(void* const* d_in, const int* in_sizes, int n_in,
                              void* d_out, int out_size, void* d_ws, size_t ws_size,
                              hipStream_t stream) {
    const float* I = (const float*)d_in[0];
    const float* J = (const float*)d_in[1];
    float* out = (float*)d_out;

    const size_t need2 = (size_t)2 * VOL * 12;   // 169.9 MB for both batches
    if (ws_size >= need2) {
        // merged path: B2 = 2*VOL u32x2, then B1 = 2*VOL u32
        u32x2* B2 = (u32x2*)d_ws;
        unsigned int* B1 = (unsigned int*)((char*)d_ws + (size_t)2 * VOL * 8);
        wh_pass<<<dim3(WDIM * NCH, 2), 192, 0, stream>>>(I, J, B2, B1, out);
        d_pass <<<dim3(WDIM * 8, 2), 192, 0, stream>>>(B2, B1, I, J, out);
    } else {
        // serial fallback: one batch volume (VOL*12 bytes)
        u32x2* B2 = (u32x2*)d_ws;
        unsigned int* B1 = (unsigned int*)((char*)d_ws + (size_t)VOL * 8);
        for (int b = 0; b < 2; ++b) {
            const float* Ib = I + (size_t)b * VOL;
            const float* Jb = J + (size_t)b * VOL;
            wh_pass<<<dim3(WDIM * NCH, 1), 192, 0, stream>>>(Ib, Jb, B2, B1,
                                                             b == 0 ? out : nullptr);
            d_pass <<<dim3(WDIM * 8, 1), 192, 0, stream>>>(B2, B1, Ib, Jb, out);
        }
    }
}

// Round 13
// 213.054 us; speedup vs baseline: 1.0173x; 1.0173x over previous
//
#include <hip/hip_runtime.h>
#include <hip/hip_bf16.h>

#define WDIM 192
#define PLANE (192 * 192)
#define VOL (192 * 192 * 192)
#define HC 16          // h-rows produced per block in wh_pass
#define TR (HC + 8)    // tile rows incl. halo = 24
#define NCH 12         // h-chunks per plane (192/HC)
#define RWU 100        // uints per padded LDS row: 200 f16 = [2 pad][96 data][2 pad] pairs
#define DC 24          // d-slices per block in d_pass

typedef __fp16 h2f __attribute__((ext_vector_type(2)));
typedef unsigned int u32x2 __attribute__((ext_vector_type(2)));

// ---- f16 helpers (wh_pass LDS staging + dot2 window sums) ----
static __device__ inline unsigned int pk_h16(float a, float b) {
    h2f v = __builtin_amdgcn_cvt_pkrtz(a, b);
    return __builtin_bit_cast(unsigned int, v);
}
static __device__ inline float h_hi(unsigned int u) {
    h2f v = __builtin_bit_cast(h2f, u); return (float)v.y;
}
// f32 += dot(f16pair, f16pair)
static __device__ inline float dot2u(unsigned int a, unsigned int b, float c) {
    return __builtin_amdgcn_fdot2(__builtin_bit_cast(h2f, a),
                                  __builtin_bit_cast(h2f, b), c, false);
}

// ---- bf16 record helpers (B format; unpack is pure bit-ops in d_pass) ----
static __device__ inline unsigned int pk_bf16(float a, float b) {
    union { __hip_bfloat162 v; unsigned int u; } cvt;
    cvt.v = __float22bfloat162_rn(make_float2(a, b));
    return cvt.u;
}
static __device__ inline float bf_lo(unsigned int u) {
    union { unsigned int u; float f; } c; c.u = u << 16; return c.f;
}
static __device__ inline float bf_hi(unsigned int u) {
    union { unsigned int u; float f; } c; c.u = u & 0xffff0000u; return c.f;
}

// --- Pass 1: fused W-box + H-box sums -> split-stream records --------------
// B2[idx] = {bf16(s0,s1), bf16(s2,s3)} (8B)
// B1[idx] = {lo: bf16(s4), hi: f16(center_I)} (4B) -- center embedded FREE
// in B1's dead half (R7 delay-line extraction, zero extra write bytes).
// Both nontemporal (early L2 evict -> d_pass reads clean L3, the R9 win).
// grid (2304, nb): x = d*12 + h_chunk, y = batch.
__global__ __launch_bounds__(192) void wh_pass(const float* __restrict__ I,
                                               const float* __restrict__ J,
                                               u32x2* __restrict__ B2,
                                               unsigned int* __restrict__ B1,
                                               float* __restrict__ out0) {
    __shared__ unsigned int sI[TR * RWU];   // 9600 B
    __shared__ unsigned int sJ[TR * RWU];   // 9600 B
    const int t = threadIdx.x;           // w
    const int d = blockIdx.x / NCH;
    const int c = blockIdx.x - d * NCH;
    const int h0 = c * HC;

    // fold output zeroing into this dispatch (stream-ordered before d_pass)
    if (out0 && blockIdx.x == 0 && blockIdx.y == 0 && t == 0) *out0 = 0.0f;

    const size_t bofs = (size_t)blockIdx.y * VOL;
    const float* Ib = I + bofs;
    const float* Jb = J + bofs;
    u32x2* B2b = B2 + bofs;
    unsigned int* B1b = B1 + bofs;

    const size_t dbase = (size_t)d * PLANE;

    // zero the 4 pad pair-slots of each row in both arrays (TR*8 = 192)
    {
        const int row = t >> 3;
        const int p = t & 7;
        unsigned int* dst = (p < 4) ? sI : sJ;
        const int q = p & 3;
        const int col = (q < 2) ? q : (96 + q);   // {0,1,98,99}
        dst[row * RWU + col] = 0u;
    }

    // cooperative staging: rows 0..23, data pairs at uint index 2 + w/2
    #pragma unroll
    for (int i = 0; i < 6; ++i) {
        const int idx4 = i * 192 + t;        // 0..1151
        const int row  = idx4 / 48;          // 0..23
        const int col4 = (idx4 - row * 48) * 4;
        const int h = h0 - 4 + row;
        float4 vI = make_float4(0.f, 0.f, 0.f, 0.f);
        float4 vJ = vI;
        if (h >= 0 && h < WDIM) {
            vI = *(const float4*)(Ib + dbase + (size_t)h * WDIM + col4);
            vJ = *(const float4*)(Jb + dbase + (size_t)h * WDIM + col4);
        }
        uint2 uI, uJ;
        uI.x = pk_h16(vI.x, vI.y); uI.y = pk_h16(vI.z, vI.w);
        uJ.x = pk_h16(vJ.x, vJ.y); uJ.y = pk_h16(vJ.z, vJ.w);
        const int ui = row * RWU + 2 + (col4 >> 1);   // even -> 8B aligned
        *(uint2*)&sI[ui] = uI;
        *(uint2*)&sJ[ui] = uJ;
    }
    __syncthreads();

    // window for output w=t covers f16 elements E=t..t+8 -> pairs tb..tb+4
    const int tb = t >> 1;
    const int odd = t & 1;
    const unsigned int ONESF = 0x3C003C00u;                       // (1,1) f16
    const unsigned int ones0 = odd ? 0x3C000000u : ONESF;         // edge ones
    const unsigned int ones4 = odd ? ONESF : 0x00003C00u;
    const unsigned int keep0 = odd ? 0xFFFF0000u : 0xFFFFFFFFu;   // operand masks
    const unsigned int keep4 = odd ? 0xFFFFFFFFu : 0x0000FFFFu;

    float ring0[9], ring1[9], ring2[9], ring3[9], ring4[9];
    #pragma unroll
    for (int j = 0; j < 9; ++j) { ring0[j]=0.f; ring1[j]=0.f; ring2[j]=0.f; ring3[j]=0.f; ring4[j]=0.f; }
    float s0 = 0.f, s1 = 0.f, s2 = 0.f, s3 = 0.f, s4 = 0.f;

    unsigned int cen[5];   // 5-deep delay: f16 center-I of tile row s
    #pragma unroll
    for (int j = 0; j < 5; ++j) cen[j] = 0u;

    unsigned int AI[5], AJ[5], BI[5], BJ[5];
    #pragma unroll
    for (int p = 0; p < 5; ++p) { AI[p] = sI[tb + p]; AJ[p] = sJ[tb + p]; }

    #pragma unroll
    for (int s = 0; s < TR; ++s) {
        if (s + 1 < TR) {
            const int base = (s + 1) * RWU + tb;
            if ((s & 1) == 0) {
                #pragma unroll
                for (int p = 0; p < 5; ++p) { BI[p] = sI[base + p]; BJ[p] = sJ[base + p]; }
            } else {
                #pragma unroll
                for (int p = 0; p < 5; ++p) { AI[p] = sI[base + p]; AJ[p] = sJ[base + p]; }
            }
        }
        const unsigned int c0 = ((s & 1) == 0) ? AI[0] : BI[0];
        const unsigned int c1 = ((s & 1) == 0) ? AI[1] : BI[1];
        const unsigned int c2 = ((s & 1) == 0) ? AI[2] : BI[2];
        const unsigned int c3 = ((s & 1) == 0) ? AI[3] : BI[3];
        const unsigned int c4 = ((s & 1) == 0) ? AI[4] : BI[4];
        const unsigned int e0 = ((s & 1) == 0) ? AJ[0] : BJ[0];
        const unsigned int e1 = ((s & 1) == 0) ? AJ[1] : BJ[1];
        const unsigned int e2 = ((s & 1) == 0) ? AJ[2] : BJ[2];
        const unsigned int e3 = ((s & 1) == 0) ? AJ[3] : BJ[3];
        const unsigned int e4 = ((s & 1) == 0) ? AJ[4] : BJ[4];

        // f16 center-I for row (h0-4+s), element w=t (bits from staged pair)
        cen[s % 5] = odd ? (c0 >> 16) : (c0 & 0xffffu);

        const unsigned int mI0 = c0 & keep0, mI4 = c4 & keep4;
        const unsigned int mJ0 = e0 & keep0, mJ4 = e4 & keep4;

        float w0 = dot2u(c0, ones0, 0.f);
        w0 = dot2u(c1, ONESF, w0); w0 = dot2u(c2, ONESF, w0);
        w0 = dot2u(c3, ONESF, w0); w0 = dot2u(c4, ones4, w0);

        float w1 = dot2u(e0, ones0, 0.f);
        w1 = dot2u(e1, ONESF, w1); w1 = dot2u(e2, ONESF, w1);
        w1 = dot2u(e3, ONESF, w1); w1 = dot2u(e4, ones4, w1);

        float w2 = dot2u(mI0, c0, 0.f);
        w2 = dot2u(c1, c1, w2); w2 = dot2u(c2, c2, w2);
        w2 = dot2u(c3, c3, w2); w2 = dot2u(mI4, c4, w2);

        float w3 = dot2u(mJ0, e0, 0.f);
        w3 = dot2u(e1, e1, w3); w3 = dot2u(e2, e2, w3);
        w3 = dot2u(e3, e3, w3); w3 = dot2u(mJ4, e4, w3);

        float w4 = dot2u(mI0, e0, 0.f);
        w4 = dot2u(c1, e1, w4); w4 = dot2u(c2, e2, w4);
        w4 = dot2u(c3, e3, w4); w4 = dot2u(mI4, e4, w4);

        const int j = s % 9;
        s0 += w0 - ring0[j]; ring0[j] = w0;
        s1 += w1 - ring1[j]; ring1[j] = w1;
        s2 += w2 - ring2[j]; ring2[j] = w2;
        s3 += w3 - ring3[j]; ring3[j] = w3;
        s4 += w4 - ring4[j]; ring4[j] = w4;

        if (s >= 8) {
            const int h_out = h0 + s - 8;
            const size_t idx = dbase + (size_t)h_out * WDIM + t;
            u32x2 v2; v2.x = pk_bf16(s0, s1); v2.y = pk_bf16(s2, s3);
            __builtin_nontemporal_store(v2, B2b + idx);
            // lo: bf16(s4); hi: f16 center-I of row h_out (= tile row s-4)
            __builtin_nontemporal_store(pk_bf16(s4, 0.f) | (cen[(s - 4) % 5] << 16),
                                        B1b + idx);
        }
    }
}

// --- Pass 2: D-axis sliding box sum + NCC + reduction ----------------------
// 3 loads/step: B2 (dwordx2), B1 (dword: s4 + embedded f16 center-I),
// J center (dword). Center-I comes from the step-(s-4) B1 word via a 5-deep
// delay line. R5-measured structure otherwise: DC=24, f32 rings, 4 groups
// of 8, register prefetch, rcp.  grid (1536, nb): x = h*8 + chunk.
__global__ __launch_bounds__(192) void d_pass(const u32x2* __restrict__ B2,
                                              const unsigned int* __restrict__ B1,
                                              const float* __restrict__ J,
                                              float* __restrict__ out) {
    const int t = threadIdx.x;
    const int h = blockIdx.x >> 3;
    const int c = blockIdx.x & 7;
    const int d0 = c * DC;
    const int base_h = h * WDIM + t;

    const size_t bofs = (size_t)blockIdx.y * VOL;
    const float* Jb = J + bofs;
    const u32x2* B2b = B2 + bofs;
    const unsigned int* B1b = B1 + bofs;

    float r0[9], r1[9], r2[9], r3[9], r4[9];
    #pragma unroll
    for (int j = 0; j < 9; ++j) { r0[j]=0.f; r1[j]=0.f; r2[j]=0.f; r3[j]=0.f; r4[j]=0.f; }
    float s0 = 0.f, s1 = 0.f, s2 = 0.f, s3 = 0.f, s4 = 0.f;

    unsigned int cden[5];   // delay of B1 word (embedded center-I in hi bits)
    #pragma unroll
    for (int j = 0; j < 5; ++j) cden[j] = 0u;

    const float inv_k = 1.0f / 729.0f;
    float local = 0.f;

    uint3 qA[8], qB[8];
    float cA[8], cB[8];
    // preload group 0 records (steps 0..7, d_in = d0-4 .. d0+3); no outputs yet
    #pragma unroll
    for (int i = 0; i < 8; ++i) {
        const int d_in = d0 - 4 + i;
        qA[i] = make_uint3(0u, 0u, 0u);
        if (d_in >= 0 && d_in < WDIM) {
            const size_t pos = (size_t)d_in * PLANE + base_h;
            const u32x2 v2 = B2b[pos];
            qA[i] = make_uint3(v2.x, v2.y, B1b[pos]);
        }
        cA[i] = 0.f;
    }

    #pragma unroll
    for (int g = 0; g < 4; ++g) {
        // prefetch group g+1: records + J centers
        if (g + 1 < 4) {
            #pragma unroll
            for (int i = 0; i < 8; ++i) {
                const int s = (g + 1) * 8 + i;
                const int d_in = d0 - 4 + s;
                uint3 v = make_uint3(0u, 0u, 0u);
                if (d_in >= 0 && d_in < WDIM) {
                    const size_t pos = (size_t)d_in * PLANE + base_h;
                    const u32x2 v2 = B2b[pos];
                    v = make_uint3(v2.x, v2.y, B1b[pos]);
                }
                const int d_out = d0 + s - 8;              // always in [0,192)
                const float cj = Jb[(size_t)d_out * PLANE + base_h];
                if ((g & 1) == 0) { qB[i] = v; cB[i] = cj; }
                else              { qA[i] = v; cA[i] = cj; }
            }
        }
        // process group g
        #pragma unroll
        for (int i = 0; i < 8; ++i) {
            const int s = g * 8 + i;
            const uint3 q = ((g & 1) == 0) ? qA[i] : qB[i];
            const float f0 = bf_lo(q.x), f1 = bf_hi(q.x);
            const float f2 = bf_lo(q.y), f3 = bf_hi(q.y);
            const float f4 = bf_lo(q.z);          // hi bits shift out
            const int j = s % 9;
            s0 += f0 - r0[j]; r0[j] = f0;
            s1 += f1 - r1[j]; r1[j] = f1;
            s2 += f2 - r2[j]; r2[j] = f2;
            s3 += f3 - r3[j]; r3[j] = f3;
            s4 += f4 - r4[j]; r4[j] = f4;
            cden[s % 5] = q.z;

            if (s >= 8) {
                // center-I: record at d_in == d_out arrived 4 steps ago
                const float Iu = h_hi(cden[(s - 4) % 5]) * inv_k;
                const float Ju = (((g & 1) == 0) ? cA[i] : cB[i]) * inv_k;
                const float cross = s4 - s0 * Ju - s1 * Iu + Iu * Ju * 729.0f;
                const float Ivar  = s2 - 2.0f * s0 * Iu + Iu * Iu * 729.0f;
                const float Jvar  = s3 - 2.0f * s1 * Ju + Ju * Ju * 729.0f;
                local += (cross * cross) * __builtin_amdgcn_rcpf(Ivar * Jvar + 1e-5f);
            }
        }
    }

    __shared__ float sred[192];
    sred[t] = local;
    __syncthreads();
    if (t < 64) {
        float v = sred[t] + sred[t + 64] + sred[t + 128];
        #pragma unroll
        for (int off = 32; off; off >>= 1) v += __shfl_down(v, off);
        if (t == 0) {
            atomicAdd(out, v * (-1.0f / 14155776.0f));
        }
    }
}

extern "C" void kernel_launch(void* const* d_in, const int* in_sizes, int n_in,
                              void* d_out, int out_size, void* d_ws, size_t ws_size,
                              hipStream_t stream) {
    const float* I = (const float*)d_in[0];
    const float* J = (const float*)d_in[1];
    float* out = (float*)d_out;

    const size_t need2 = (size_t)2 * VOL * 12;   // 169.9 MB for both batches
    if (ws_size >= need2) {
        // merged path: B2 = 2*VOL u32x2, then B1 = 2*VOL u32
        u32x2* B2 = (u32x2*)d_ws;
        unsigned int* B1 = (unsigned int*)((char*)d_ws + (size_t)2 * VOL * 8);
        wh_pass<<<dim3(WDIM * NCH, 2), 192, 0, stream>>>(I, J, B2, B1, out);
        d_pass <<<dim3(WDIM * 8, 2), 192, 0, stream>>>(B2, B1, J, out);
    } else {
        // serial fallback: one batch volume (VOL*12 bytes)
        u32x2* B2 = (u32x2*)d_ws;
        unsigned int* B1 = (unsigned int*)((char*)d_ws + (size_t)VOL * 8);
        for (int b = 0; b < 2; ++b) {
            const float* Ib = I + (size_t)b * VOL;
            const float* Jb = J + (size_t)b * VOL;
            wh_pass<<<dim3(WDIM * NCH, 1), 192, 0, stream>>>(Ib, Jb, B2, B1,
                                                             b == 0 ? out : nullptr);
            d_pass <<<dim3(WDIM * 8, 1), 192, 0, stream>>>(B2, B1, Jb, out);
        }
    }
}

// Round 14
// 212.794 us; speedup vs baseline: 1.0186x; 1.0012x over previous
//
#include <hip/hip_runtime.h>
#include <hip/hip_bf16.h>

#define WDIM 192
#define PLANE (192 * 192)
#define VOL (192 * 192 * 192)
#define HC 24          // h-rows produced per block in wh_pass
#define TR (HC + 8)    // tile rows incl. halo = 32
#define NCH 8          // h-chunks per plane (192/HC)
#define RWU 100        // uints per padded LDS row: 200 f16 = [2 pad][96 data][2 pad] pairs
#define DC 24          // d-slices per block in d_pass

typedef __fp16 h2f __attribute__((ext_vector_type(2)));
typedef unsigned int u32x2 __attribute__((ext_vector_type(2)));

// ---- f16 helpers (wh_pass LDS staging + dot2 window sums) ----
static __device__ inline unsigned int pk_h16(float a, float b) {
    h2f v = __builtin_amdgcn_cvt_pkrtz(a, b);
    return __builtin_bit_cast(unsigned int, v);
}
static __device__ inline float h_hi(unsigned int u) {
    h2f v = __builtin_bit_cast(h2f, u); return (float)v.y;
}
// f32 += dot(f16pair, f16pair)
static __device__ inline float dot2u(unsigned int a, unsigned int b, float c) {
    return __builtin_amdgcn_fdot2(__builtin_bit_cast(h2f, a),
                                  __builtin_bit_cast(h2f, b), c, false);
}

// ---- bf16 record helpers (B format; unpack is pure bit-ops in d_pass) ----
static __device__ inline unsigned int pk_bf16(float a, float b) {
    union { __hip_bfloat162 v; unsigned int u; } cvt;
    cvt.v = __float22bfloat162_rn(make_float2(a, b));
    return cvt.u;
}
static __device__ inline float bf_lo(unsigned int u) {
    union { unsigned int u; float f; } c; c.u = u << 16; return c.f;
}
static __device__ inline float bf_hi(unsigned int u) {
    union { unsigned int u; float f; } c; c.u = u & 0xffff0000u; return c.f;
}

// --- Pass 1: fused W-box + H-box sums -> split-stream records --------------
// B2[idx] = {bf16(s0,s1), bf16(s2,s3)} (8B)
// B1[idx] = {lo: bf16(s4), hi: f16(center_I)} (4B) -- center embedded FREE
// in B1's dead half (delay-line extraction, zero extra write bytes).
// Both nontemporal (early L2 evict -> d_pass reads clean L3, the R9 win).
// HC=24: steps/output 1.33 (was 1.5 at HC=16) -> -11% inner work.
// grid (1536, nb): x = d*8 + h_chunk, y = batch.
__global__ __launch_bounds__(192) void wh_pass(const float* __restrict__ I,
                                               const float* __restrict__ J,
                                               u32x2* __restrict__ B2,
                                               unsigned int* __restrict__ B1,
                                               float* __restrict__ out0) {
    __shared__ unsigned int sI[TR * RWU];   // 12800 B
    __shared__ unsigned int sJ[TR * RWU];   // 12800 B
    const int t = threadIdx.x;           // w
    const int d = blockIdx.x >> 3;
    const int c = blockIdx.x & 7;
    const int h0 = c * HC;

    // fold output zeroing into this dispatch (stream-ordered before d_pass)
    if (out0 && blockIdx.x == 0 && blockIdx.y == 0 && t == 0) *out0 = 0.0f;

    const size_t bofs = (size_t)blockIdx.y * VOL;
    const float* Ib = I + bofs;
    const float* Jb = J + bofs;
    u32x2* B2b = B2 + bofs;
    unsigned int* B1b = B1 + bofs;

    const size_t dbase = (size_t)d * PLANE;

    // zero the 4 pad pair-slots of each row in both arrays (TR*8 = 256)
    for (int n = t; n < TR * 8; n += 192) {
        const int row = n >> 3;
        const int p = n & 7;
        unsigned int* dst = (p < 4) ? sI : sJ;
        const int q = p & 3;
        const int col = (q < 2) ? q : (96 + q);   // {0,1,98,99}
        dst[row * RWU + col] = 0u;
    }

    // cooperative staging: rows 0..31, data pairs at uint index 2 + w/2
    #pragma unroll
    for (int i = 0; i < TR * 48 / 192; ++i) {    // 8 iters
        const int idx4 = i * 192 + t;        // 0..1535
        const int row  = idx4 / 48;          // 0..31
        const int col4 = (idx4 - row * 48) * 4;
        const int h = h0 - 4 + row;
        float4 vI = make_float4(0.f, 0.f, 0.f, 0.f);
        float4 vJ = vI;
        if (h >= 0 && h < WDIM) {
            vI = *(const float4*)(Ib + dbase + (size_t)h * WDIM + col4);
            vJ = *(const float4*)(Jb + dbase + (size_t)h * WDIM + col4);
        }
        uint2 uI, uJ;
        uI.x = pk_h16(vI.x, vI.y); uI.y = pk_h16(vI.z, vI.w);
        uJ.x = pk_h16(vJ.x, vJ.y); uJ.y = pk_h16(vJ.z, vJ.w);
        const int ui = row * RWU + 2 + (col4 >> 1);   // even -> 8B aligned
        *(uint2*)&sI[ui] = uI;
        *(uint2*)&sJ[ui] = uJ;
    }
    __syncthreads();

    // window for output w=t covers f16 elements E=t..t+8 -> pairs tb..tb+4
    const int tb = t >> 1;
    const int odd = t & 1;
    const unsigned int ONESF = 0x3C003C00u;                       // (1,1) f16
    const unsigned int ones0 = odd ? 0x3C000000u : ONESF;         // edge ones
    const unsigned int ones4 = odd ? ONESF : 0x00003C00u;
    const unsigned int keep0 = odd ? 0xFFFF0000u : 0xFFFFFFFFu;   // operand masks
    const unsigned int keep4 = odd ? 0xFFFFFFFFu : 0x0000FFFFu;

    float ring0[9], ring1[9], ring2[9], ring3[9], ring4[9];
    #pragma unroll
    for (int j = 0; j < 9; ++j) { ring0[j]=0.f; ring1[j]=0.f; ring2[j]=0.f; ring3[j]=0.f; ring4[j]=0.f; }
    float s0 = 0.f, s1 = 0.f, s2 = 0.f, s3 = 0.f, s4 = 0.f;

    unsigned int cen[5];   // 5-deep delay: f16 center-I of tile row s
    #pragma unroll
    for (int j = 0; j < 5; ++j) cen[j] = 0u;

    unsigned int AI[5], AJ[5], BI[5], BJ[5];
    #pragma unroll
    for (int p = 0; p < 5; ++p) { AI[p] = sI[tb + p]; AJ[p] = sJ[tb + p]; }

    #pragma unroll
    for (int s = 0; s < TR; ++s) {
        if (s + 1 < TR) {
            const int base = (s + 1) * RWU + tb;
            if ((s & 1) == 0) {
                #pragma unroll
                for (int p = 0; p < 5; ++p) { BI[p] = sI[base + p]; BJ[p] = sJ[base + p]; }
            } else {
                #pragma unroll
                for (int p = 0; p < 5; ++p) { AI[p] = sI[base + p]; AJ[p] = sJ[base + p]; }
            }
        }
        const unsigned int c0 = ((s & 1) == 0) ? AI[0] : BI[0];
        const unsigned int c1 = ((s & 1) == 0) ? AI[1] : BI[1];
        const unsigned int c2 = ((s & 1) == 0) ? AI[2] : BI[2];
        const unsigned int c3 = ((s & 1) == 0) ? AI[3] : BI[3];
        const unsigned int c4 = ((s & 1) == 0) ? AI[4] : BI[4];
        const unsigned int e0 = ((s & 1) == 0) ? AJ[0] : BJ[0];
        const unsigned int e1 = ((s & 1) == 0) ? AJ[1] : BJ[1];
        const unsigned int e2 = ((s & 1) == 0) ? AJ[2] : BJ[2];
        const unsigned int e3 = ((s & 1) == 0) ? AJ[3] : BJ[3];
        const unsigned int e4 = ((s & 1) == 0) ? AJ[4] : BJ[4];

        // f16 center-I for row (h0-4+s), element w=t (bits from staged pair)
        cen[s % 5] = odd ? (c0 >> 16) : (c0 & 0xffffu);

        const unsigned int mI0 = c0 & keep0, mI4 = c4 & keep4;
        const unsigned int mJ0 = e0 & keep0, mJ4 = e4 & keep4;

        float w0 = dot2u(c0, ones0, 0.f);
        w0 = dot2u(c1, ONESF, w0); w0 = dot2u(c2, ONESF, w0);
        w0 = dot2u(c3, ONESF, w0); w0 = dot2u(c4, ones4, w0);

        float w1 = dot2u(e0, ones0, 0.f);
        w1 = dot2u(e1, ONESF, w1); w1 = dot2u(e2, ONESF, w1);
        w1 = dot2u(e3, ONESF, w1); w1 = dot2u(e4, ones4, w1);

        float w2 = dot2u(mI0, c0, 0.f);
        w2 = dot2u(c1, c1, w2); w2 = dot2u(c2, c2, w2);
        w2 = dot2u(c3, c3, w2); w2 = dot2u(mI4, c4, w2);

        float w3 = dot2u(mJ0, e0, 0.f);
        w3 = dot2u(e1, e1, w3); w3 = dot2u(e2, e2, w3);
        w3 = dot2u(e3, e3, w3); w3 = dot2u(mJ4, e4, w3);

        float w4 = dot2u(mI0, e0, 0.f);
        w4 = dot2u(c1, e1, w4); w4 = dot2u(c2, e2, w4);
        w4 = dot2u(c3, e3, w4); w4 = dot2u(mI4, e4, w4);

        const int j = s % 9;
        s0 += w0 - ring0[j]; ring0[j] = w0;
        s1 += w1 - ring1[j]; ring1[j] = w1;
        s2 += w2 - ring2[j]; ring2[j] = w2;
        s3 += w3 - ring3[j]; ring3[j] = w3;
        s4 += w4 - ring4[j]; ring4[j] = w4;

        if (s >= 8) {
            const int h_out = h0 + s - 8;
            const size_t idx = dbase + (size_t)h_out * WDIM + t;
            u32x2 v2; v2.x = pk_bf16(s0, s1); v2.y = pk_bf16(s2, s3);
            __builtin_nontemporal_store(v2, B2b + idx);
            // lo: bf16(s4); hi: f16 center-I of row h_out (= tile row s-4)
            __builtin_nontemporal_store(pk_bf16(s4, 0.f) | (cen[(s - 4) % 5] << 16),
                                        B1b + idx);
        }
    }
}

// --- Pass 2: D-axis sliding box sum + NCC + reduction ----------------------
// (byte-identical to R13) 3 loads/step: B2 (dwordx2), B1 (dword: s4 +
// embedded f16 center-I), J center (dword). Center-I via 5-deep delay line.
// DC=24, f32 rings, 4 groups of 8, register prefetch, rcp.
// grid (1536, nb): x = h*8 + chunk.
__global__ __launch_bounds__(192) void d_pass(const u32x2* __restrict__ B2,
                                              const unsigned int* __restrict__ B1,
                                              const float* __restrict__ J,
                                              float* __restrict__ out) {
    const int t = threadIdx.x;
    const int h = blockIdx.x >> 3;
    const int c = blockIdx.x & 7;
    const int d0 = c * DC;
    const int base_h = h * WDIM + t;

    const size_t bofs = (size_t)blockIdx.y * VOL;
    const float* Jb = J + bofs;
    const u32x2* B2b = B2 + bofs;
    const unsigned int* B1b = B1 + bofs;

    float r0[9], r1[9], r2[9], r3[9], r4[9];
    #pragma unroll
    for (int j = 0; j < 9; ++j) { r0[j]=0.f; r1[j]=0.f; r2[j]=0.f; r3[j]=0.f; r4[j]=0.f; }
    float s0 = 0.f, s1 = 0.f, s2 = 0.f, s3 = 0.f, s4 = 0.f;

    unsigned int cden[5];   // delay of B1 word (embedded center-I in hi bits)
    #pragma unroll
    for (int j = 0; j < 5; ++j) cden[j] = 0u;

    const float inv_k = 1.0f / 729.0f;
    float local = 0.f;

    uint3 qA[8], qB[8];
    float cA[8], cB[8];
    // preload group 0 records (steps 0..7, d_in = d0-4 .. d0+3); no outputs yet
    #pragma unroll
    for (int i = 0; i < 8; ++i) {
        const int d_in = d0 - 4 + i;
        qA[i] = make_uint3(0u, 0u, 0u);
        if (d_in >= 0 && d_in < WDIM) {
            const size_t pos = (size_t)d_in * PLANE + base_h;
            const u32x2 v2 = B2b[pos];
            qA[i] = make_uint3(v2.x, v2.y, B1b[pos]);
        }
        cA[i] = 0.f;
    }

    #pragma unroll
    for (int g = 0; g < 4; ++g) {
        // prefetch group g+1: records + J centers
        if (g + 1 < 4) {
            #pragma unroll
            for (int i = 0; i < 8; ++i) {
                const int s = (g + 1) * 8 + i;
                const int d_in = d0 - 4 + s;
                uint3 v = make_uint3(0u, 0u, 0u);
                if (d_in >= 0 && d_in < WDIM) {
                    const size_t pos = (size_t)d_in * PLANE + base_h;
                    const u32x2 v2 = B2b[pos];
                    v = make_uint3(v2.x, v2.y, B1b[pos]);
                }
                const int d_out = d0 + s - 8;              // always in [0,192)
                const float cj = Jb[(size_t)d_out * PLANE + base_h];
                if ((g & 1) == 0) { qB[i] = v; cB[i] = cj; }
                else              { qA[i] = v; cA[i] = cj; }
            }
        }
        // process group g
        #pragma unroll
        for (int i = 0; i < 8; ++i) {
            const int s = g * 8 + i;
            const uint3 q = ((g & 1) == 0) ? qA[i] : qB[i];
            const float f0 = bf_lo(q.x), f1 = bf_hi(q.x);
            const float f2 = bf_lo(q.y), f3 = bf_hi(q.y);
            const float f4 = bf_lo(q.z);          // hi bits shift out
            const int j = s % 9;
            s0 += f0 - r0[j]; r0[j] = f0;
            s1 += f1 - r1[j]; r1[j] = f1;
            s2 += f2 - r2[j]; r2[j] = f2;
            s3 += f3 - r3[j]; r3[j] = f3;
            s4 += f4 - r4[j]; r4[j] = f4;
            cden[s % 5] = q.z;

            if (s >= 8) {
                // center-I: record at d_in == d_out arrived 4 steps ago
                const float Iu = h_hi(cden[(s - 4) % 5]) * inv_k;
                const float Ju = (((g & 1) == 0) ? cA[i] : cB[i]) * inv_k;
                const float cross = s4 - s0 * Ju - s1 * Iu + Iu * Ju * 729.0f;
                const float Ivar  = s2 - 2.0f * s0 * Iu + Iu * Iu * 729.0f;
                const float Jvar  = s3 - 2.0f * s1 * Ju + Ju * Ju * 729.0f;
                local += (cross * cross) * __builtin_amdgcn_rcpf(Ivar * Jvar + 1e-5f);
            }
        }
    }

    __shared__ float sred[192];
    sred[t] = local;
    __syncthreads();
    if (t < 64) {
        float v = sred[t] + sred[t + 64] + sred[t + 128];
        #pragma unroll
        for (int off = 32; off; off >>= 1) v += __shfl_down(v, off);
        if (t == 0) {
            atomicAdd(out, v * (-1.0f / 14155776.0f));
        }
    }
}

extern "C" void kernel_launch(void* const* d_in, const int* in_sizes, int n_in,
                              void* d_out, int out_size, void* d_ws, size_t ws_size,
                              hipStream_t stream) {
    const float* I = (const float*)d_in[0];
    const float* J = (const float*)d_in[1];
    float* out = (float*)d_out;

    const size_t need2 = (size_t)2 * VOL * 12;   // 169.9 MB for both batches
    if (ws_size >= need2) {
        // merged path: B2 = 2*VOL u32x2, then B1 = 2*VOL u32
        u32x2* B2 = (u32x2*)d_ws;
        unsigned int* B1 = (unsigned int*)((char*)d_ws + (size_t)2 * VOL * 8);
        wh_pass<<<dim3(WDIM * NCH, 2), 192, 0, stream>>>(I, J, B2, B1, out);
        d_pass <<<dim3(WDIM * 8, 2), 192, 0, stream>>>(B2, B1, J, out);
    } else {
        // serial fallback: one batch volume (VOL*12 bytes)
        u32x2* B2 = (u32x2*)d_ws;
        unsigned int* B1 = (unsigned int*)((char*)d_ws + (size_t)VOL * 8);
        for (int b = 0; b < 2; ++b) {
            const float* Ib = I + (size_t)b * VOL;
            const float* Jb = J + (size_t)b * VOL;
            wh_pass<<<dim3(WDIM * NCH, 1), 192, 0, stream>>>(Ib, Jb, B2, B1,
                                                             b == 0 ? out : nullptr);
            d_pass <<<dim3(WDIM * 8, 1), 192, 0, stream>>>(B2, B1, Jb, out);
        }
    }
}